// Round 2
// baseline (3193.905 us; speedup 1.0000x reference)
//
#include <hip/hip_runtime.h>
#include <hip/hip_fp16.h>
#include <stdint.h>

// MDRNN: 2-level bidirectional LSTM over S=2048 steps, B=64, H=128, I=256, O=88.
// All inputs/outputs are FP32 (per reference). Internal compute fp16 + fp32 acc.
// Phases:
//  1) convert x (fp32 -> fp16, layout [b][s][k] -> [s][b][k])
//  2) convert weights fp32 -> fp16
//  3) GEMM: Gt = xh @ Wt_ih^T            [131072,256]x[256,1024]  (MFMA fp16)
//  4) time LSTM scan (128 WGs = batch x dir), writes tout fp16 [s][b][256]
//  5) GEMM: Gp = tout @ Wp_ih^T          (reuses G buffer)
//  6) pitch LSTM scan, writes final h [64][256] fp32
//  7) output projection -> d_out fp32 [64][88]

typedef _Float16 f16;
typedef _Float16 f16x2 __attribute__((ext_vector_type(2)));
typedef _Float16 f16x8 __attribute__((ext_vector_type(8)));
typedef float f32x4 __attribute__((ext_vector_type(4)));

#if defined(__has_builtin)
#if __has_builtin(__builtin_amdgcn_fdot2)
#define HAVE_FDOT2 1
#endif
#endif

static __device__ __forceinline__ float fdot2a(uint32_t a, uint32_t b, float c) {
#ifdef HAVE_FDOT2
    return __builtin_amdgcn_fdot2(__builtin_bit_cast(f16x2, a),
                                  __builtin_bit_cast(f16x2, b), c, false);
#else
    f16x2 av = __builtin_bit_cast(f16x2, a), bv = __builtin_bit_cast(f16x2, b);
    return c + (float)av.x * (float)bv.x + (float)av.y * (float)bv.y;
#endif
}

static __device__ __forceinline__ float fsig(float x)  { return 1.f / (1.f + __expf(-x)); }
static __device__ __forceinline__ float ftanh(float x) { return 1.f - 2.f / (__expf(2.f * x) + 1.f); }

// ---------------- conversions ----------------

__global__ __launch_bounds__(256) void k_convert_x(const float* __restrict__ x,
                                                   f16* __restrict__ xh) {
    // x: [64][2048][256] fp32 ; xh: [2048][64][256] fp16
    int id = blockIdx.x * 256 + threadIdx.x;   // 4,194,304 total (8 elems each)
    int k8 = id & 31;
    int sb = id >> 5;
    int s = sb & 2047;
    int b = sb >> 11;
    const float4* src = (const float4*)(x + (((size_t)b * 2048 + s) << 8) + (k8 << 3));
    float4 v0 = src[0], v1 = src[1];
    f16x8 o = {(f16)v0.x, (f16)v0.y, (f16)v0.z, (f16)v0.w,
               (f16)v1.x, (f16)v1.y, (f16)v1.z, (f16)v1.w};
    *(f16x8*)(xh + (((size_t)s * 64 + b) << 8) + (k8 << 3)) = o;
}

__global__ __launch_bounds__(256) void k_convert_w(const float* __restrict__ src,
                                                   f16* __restrict__ dst, int n8) {
    int id = blockIdx.x * 256 + threadIdx.x;
    if (id >= n8) return;
    const float4* sp = (const float4*)(src + (size_t)id * 8);
    float4 v0 = sp[0], v1 = sp[1];
    f16x8 o = {(f16)v0.x, (f16)v0.y, (f16)v0.z, (f16)v0.w,
               (f16)v1.x, (f16)v1.y, (f16)v1.z, (f16)v1.w};
    *(f16x8*)(dst + (size_t)id * 8) = o;
}

// ---------------- MFMA GEMM: C[M][N] = A[M][K] * B[N][K]^T  (fp16 in, fp16 out) ----------------

#define BM 128
#define BN 128
#define BKK 32
#define LDT 40   // padded LDS row stride (fp16 elems)

__global__ __launch_bounds__(256) void k_gemm(const f16* __restrict__ A,
                                              const f16* __restrict__ B,
                                              f16* __restrict__ C,
                                              int M, int N, int K) {
    __shared__ __align__(16) f16 As[BM * LDT];
    __shared__ __align__(16) f16 Bs[BN * LDT];
    const int tid  = threadIdx.x;
    const int m0   = blockIdx.x * BM;
    const int n0   = blockIdx.y * BN;
    const int lane = tid & 63;
    const int wave = tid >> 6;
    const int wm   = (wave & 1) * 64;
    const int wn   = (wave >> 1) * 64;
    const int r    = tid >> 1;            // staging row 0..127
    const int koff = (tid & 1) * 16;      // staging k-offset (fp16 elems)
    const int mrow = lane & 15;
    const int kof  = (lane >> 4) * 8;

    f32x4 acc[4][4];
#pragma unroll
    for (int i = 0; i < 4; ++i)
#pragma unroll
        for (int j = 0; j < 4; ++j) acc[i][j] = (f32x4){0.f, 0.f, 0.f, 0.f};

    for (int k0 = 0; k0 < K; k0 += BKK) {
        uint4 a0 = *(const uint4*)(A + (size_t)(m0 + r) * K + k0 + koff);
        uint4 a1 = *(const uint4*)(A + (size_t)(m0 + r) * K + k0 + koff + 8);
        uint4 b0 = *(const uint4*)(B + (size_t)(n0 + r) * K + k0 + koff);
        uint4 b1 = *(const uint4*)(B + (size_t)(n0 + r) * K + k0 + koff + 8);
        *(uint4*)(As + r * LDT + koff)     = a0;
        *(uint4*)(As + r * LDT + koff + 8) = a1;
        *(uint4*)(Bs + r * LDT + koff)     = b0;
        *(uint4*)(Bs + r * LDT + koff + 8) = b1;
        __syncthreads();
        f16x8 af[4], bfr[4];
#pragma unroll
        for (int i = 0; i < 4; ++i)
            af[i] = *(const f16x8*)(As + (wm + i * 16 + mrow) * LDT + kof);
#pragma unroll
        for (int j = 0; j < 4; ++j)
            bfr[j] = *(const f16x8*)(Bs + (wn + j * 16 + mrow) * LDT + kof);
#pragma unroll
        for (int i = 0; i < 4; ++i)
#pragma unroll
            for (int j = 0; j < 4; ++j)
                acc[i][j] = __builtin_amdgcn_mfma_f32_16x16x32_f16(af[i], bfr[j], acc[i][j], 0, 0, 0);
        __syncthreads();
    }
    // C/D layout: col = lane&15 (N side), row = (lane>>4)*4 + reg (M side)
    const int crow = (lane >> 4) * 4;
#pragma unroll
    for (int i = 0; i < 4; ++i) {
#pragma unroll
        for (int j = 0; j < 4; ++j) {
            int col = n0 + wn + j * 16 + (lane & 15);
            size_t base = (size_t)(m0 + wm + i * 16 + crow) * N + col;
#pragma unroll
            for (int rr = 0; rr < 4; ++rr)
                C[base + (size_t)rr * N] = (f16)acc[i][j][rr];
        }
    }
}

// ---------------- recurrent LSTM scan ----------------
// One WG per (batch, direction). 512 threads, one gate row each.
// Whh row (128 fp16 = 64 packed dwords) held in VGPRs across all 2048 steps.

__global__ __launch_bounds__(512, 2) void k_lstm(
    const f16* __restrict__ G,              // [S][64][1024] gate preacts (x part)
    const f16* __restrict__ Whh,            // [2][512][128] fp16
    const float* __restrict__ bih,          // [2][512] fp32
    const float* __restrict__ bhh,          // [2][512] fp32
    f16* __restrict__ tout,                 // [S][64][256] fp16 (flags&1)
    float* __restrict__ hfin,               // [64][256] fp32 (flags&2)
    const int S, const int flags) {
    const int b   = blockIdx.x >> 1;
    const int dir = blockIdx.x & 1;
    const int g   = threadIdx.x;            // gate index within cell, 0..511

    __shared__ float gl[512];
    __shared__ __align__(16) f16 hsh[128];

    uint32_t w[64];
    {
        const uint4* wp = (const uint4*)(Whh + ((size_t)(dir * 512 + g)) * 128);
#pragma unroll
        for (int j = 0; j < 16; ++j) {
            uint4 q = wp[j];
            w[4 * j + 0] = q.x; w[4 * j + 1] = q.y; w[4 * j + 2] = q.z; w[4 * j + 3] = q.w;
        }
    }
    const float bias = bih[dir * 512 + g] + bhh[dir * 512 + g];
    if (g < 64) ((uint32_t*)hsh)[g] = 0u;
    float c = 0.f, h = 0.f;
    __syncthreads();

    const f16* gp = G + (size_t)b * 1024 + dir * 512 + g;
    f16 gnext = gp[0];
    for (int s = 0; s < S; ++s) {
        const f16 gcur = gnext;
        const int sn = (s + 1 < S) ? (s + 1) : s;
        gnext = gp[(size_t)sn * 65536];     // prefetch next step's gate preact
        float a0 = 0.f, a1 = 0.f;
        const uint4* hv = (const uint4*)hsh;
#pragma unroll
        for (int j = 0; j < 16; ++j) {
            uint4 hq = hv[j];               // broadcast LDS read
            a0 = fdot2a(w[4 * j + 0], hq.x, a0);
            a1 = fdot2a(w[4 * j + 1], hq.y, a1);
            a0 = fdot2a(w[4 * j + 2], hq.z, a0);
            a1 = fdot2a(w[4 * j + 3], hq.w, a1);
        }
        const float rg = (float)gcur + bias + a0 + a1;
        gl[g] = rg;
        __syncthreads();
        if (g < 128) {
            float xi = gl[g], xf = gl[128 + g], xg = gl[256 + g], xo = gl[384 + g];
            float si = fsig(xi), sf = fsig(xf), so = fsig(xo);
            float tg = ftanh(xg);
            c = sf * c + si * tg;
            h = so * ftanh(c);
            hsh[g] = (f16)h;
            if (flags & 1) tout[((size_t)s * 64 + b) * 256 + dir * 128 + g] = (f16)h;
        }
        __syncthreads();
    }
    if ((flags & 2) && g < 128) hfin[b * 256 + dir * 128 + g] = h;
}

// ---------------- output projection ----------------

__global__ __launch_bounds__(128) void k_out(const float* __restrict__ hp,  // [64][256]
                                             const float* __restrict__ Wo,  // [88][256]
                                             const float* __restrict__ bo,  // [88]
                                             float* __restrict__ out) {     // [64][88]
    const int b = blockIdx.x;
    const int t = threadIdx.x;
    __shared__ float hs[256];
    hs[t] = hp[b * 256 + t];
    hs[t + 128] = hp[b * 256 + 128 + t];
    __syncthreads();
    if (t < 88) {
        float acc = bo[t];
        const float* wr = Wo + t * 256;
#pragma unroll 4
        for (int k = 0; k < 256; ++k) acc += wr[k] * hs[k];
        out[b * 88 + t] = acc;
    }
}

// ---------------- launch ----------------

extern "C" void kernel_launch(void* const* d_in, const int* in_sizes, int n_in,
                              void* d_out, int out_size, void* d_ws, size_t ws_size,
                              hipStream_t stream) {
    const float* x    = (const float*)d_in[0];
    const float* Wtih = (const float*)d_in[1];
    const float* Wthh = (const float*)d_in[2];
    const float* btih = (const float*)d_in[3];
    const float* bthh = (const float*)d_in[4];
    const float* Wpih = (const float*)d_in[5];
    const float* Wphh = (const float*)d_in[6];
    const float* bpih = (const float*)d_in[7];
    const float* bphh = (const float*)d_in[8];
    const float* Wo   = (const float*)d_in[9];
    const float* bo   = (const float*)d_in[10];

    char* ws = (char*)d_ws;
    f16*   xh    = (f16*)(ws + 0);            //  67,108,864 B
    f16*   G     = (f16*)(ws + 67108864);     // 268,435,456 B (Gt then Gp)
    f16*   tout  = (f16*)(ws + 335544320);    //  67,108,864 B
    f16*   wtih  = (f16*)(ws + 402653184);    //     524,288 B
    f16*   wthh  = (f16*)(ws + 403177472);    //     262,144 B
    f16*   wpih  = (f16*)(ws + 403439616);    //     524,288 B
    f16*   wphh  = (f16*)(ws + 403963904);    //     262,144 B
    float* hp    = (float*)(ws + 404226048);  //      65,536 B   (total ~405 MB)

    k_convert_x<<<16384, 256, 0, stream>>>(x, xh);
    k_convert_w<<<128, 256, 0, stream>>>(Wtih, wtih, 32768);
    k_convert_w<<<64,  256, 0, stream>>>(Wthh, wthh, 16384);
    k_convert_w<<<128, 256, 0, stream>>>(Wpih, wpih, 32768);
    k_convert_w<<<64,  256, 0, stream>>>(Wphh, wphh, 16384);

    // Gt = xh @ Wt_ih^T
    k_gemm<<<dim3(1024, 8), 256, 0, stream>>>(xh, wtih, G, 131072, 1024, 256);
    // time-level scan -> tout
    k_lstm<<<128, 512, 0, stream>>>(G, wthh, btih, bthh, tout, nullptr, 2048, 1);
    // Gp = tout @ Wp_ih^T (reuse G buffer)
    k_gemm<<<dim3(1024, 8), 256, 0, stream>>>(tout, wpih, G, 131072, 1024, 256);
    // pitch-level scan -> final h
    k_lstm<<<128, 512, 0, stream>>>(G, wphh, bpih, bphh, nullptr, hp, 2048, 2);
    // output projection
    k_out<<<64, 128, 0, stream>>>(hp, Wo, bo, (float*)d_out);
}